// Round 4
// baseline (650.478 us; speedup 1.0000x reference)
//
#include <hip/hip_runtime.h>
#include <hip/hip_bf16.h>
#include <math.h>

#define NRES 768
#define CS 384
#define CZ 128
#define NH 12
#define INF_ 100000.0f
#define CAT 2112
#define LQ 776   // logits row stride (floats / shorts), multiple of 8 for 16B-aligned bf16x8 rows

typedef __attribute__((ext_vector_type(8))) short bf16x8;
typedef __attribute__((ext_vector_type(4))) float f32x4;

// Workspace layout (float offsets)
#define WS_Q      0         // 768*192  q scaled by 0.25
#define WS_K      147456    // 768*192
#define WS_QPL    294912    // 768*144  raw linear q-points
#define WS_KPL    405504    // 768*144
#define WS_VPL    516096    // 768*288
#define WS_QPT    737280    // 768*144  transformed q_pts [n][h][p][3]
#define WS_KPT    847872    // 768*144
#define WS_SQQ    958464    // 768*12
#define WS_SQK    967680    // 768*12
#define WS_VCAT   976896    // 768*480  [n][ v(192) | v_pts(288) ]
#define WS_CAT    1345536   // 768*2112

__device__ __forceinline__ short f2bf(float f) {
  union { float f; unsigned u; } x; x.f = f;
  unsigned r = x.u + 0x7FFFu + ((x.u >> 16) & 1u);
  return (short)(r >> 16);
}

__device__ __forceinline__ f32x4 mfma16(bf16x8 a, bf16x8 b, f32x4 c) {
  return __builtin_amdgcn_mfma_f32_16x16x32_bf16(a, b, c, 0, 0, 0);
}

__device__ __forceinline__ bf16x8 pack8(const float* p) {
  float4 a0 = *(const float4*)p;
  float4 a1 = *(const float4*)(p + 4);
  bf16x8 v;
  v[0] = f2bf(a0.x); v[1] = f2bf(a0.y); v[2] = f2bf(a0.z); v[3] = f2bf(a0.w);
  v[4] = f2bf(a1.x); v[5] = f2bf(a1.y); v[6] = f2bf(a1.z); v[7] = f2bf(a1.w);
  return v;
}

// ---------------- K1: all s-projections as one bf16 MFMA GEMM -----------------
// [768 x 384] @ [384 x 1152], N-tiles dispatched per weight segment.
__global__ __launch_bounds__(256) void k_proj(
    const float* __restrict__ s,
    const float* __restrict__ w_q, const float* __restrict__ w_k, const float* __restrict__ w_v,
    const float* __restrict__ w_qp, const float* __restrict__ b_qp,
    const float* __restrict__ w_kp, const float* __restrict__ b_kp,
    const float* __restrict__ w_vp, const float* __restrict__ b_vp,
    float* __restrict__ ws)
{
  int mt = blockIdx.x;                    // 0..47 (row tile)
  int wv = threadIdx.x >> 6;
  int lane = threadIdx.x & 63;
  int nt = blockIdx.y * 4 + wv;           // 0..71 (16-col tile)
  const float* W; const float* B = nullptr; int OC, j0, seg;
  if (nt < 12)      { W = w_q;  OC = 192; j0 = nt*16;       seg = 0; }
  else if (nt < 24) { W = w_k;  OC = 192; j0 = nt*16 - 192; seg = 1; }
  else if (nt < 36) { W = w_v;  OC = 192; j0 = nt*16 - 384; seg = 2; }
  else if (nt < 45) { W = w_qp; OC = 144; j0 = nt*16 - 576; seg = 3; B = b_qp; }
  else if (nt < 54) { W = w_kp; OC = 144; j0 = nt*16 - 720; seg = 4; B = b_kp; }
  else              { W = w_vp; OC = 288; j0 = nt*16 - 864; seg = 5; B = b_vp; }
  int col = lane & 15, g = lane >> 4;
  f32x4 acc = {0.f, 0.f, 0.f, 0.f};
  for (int ks = 0; ks < 12; ks++) {
    bf16x8 av = pack8(s + (size_t)(mt*16 + col)*CS + ks*32 + g*8);
    const float* bp = W + (size_t)(ks*32 + g*8)*OC + j0 + col;
    bf16x8 bv;
    #pragma unroll
    for (int j = 0; j < 8; j++) bv[j] = f2bf(bp[(size_t)j*OC]);
    acc = mfma16(av, bv, acc);
  }
  float bias = B ? B[j0 + col] : 0.f;
  float* q_ws = ws + WS_Q;  float* k_ws = ws + WS_K;
  float* qpl  = ws + WS_QPL; float* kpl = ws + WS_KPL; float* vpl = ws + WS_VPL;
  float* vcat = ws + WS_VCAT;
  int jc = j0 + col;
  #pragma unroll
  for (int r = 0; r < 4; r++) {
    int n = mt*16 + g*4 + r;
    float v = acc[r] + bias;
    switch (seg) {
      case 0: q_ws[n*192 + jc] = v * 0.25f; break;   // scalar_w = 1/sqrt(16)
      case 1: k_ws[n*192 + jc] = v; break;
      case 2: vcat[n*480 + jc] = v; break;
      case 3: qpl[n*144 + jc] = v; break;
      case 4: kpl[n*144 + jc] = v; break;
      default: vpl[n*288 + jc] = v; break;
    }
  }
}

// ---------------- K1b: rigid apply + squared norms ----------------------------
__global__ __launch_bounds__(192) void k_rigid(
    const float* __restrict__ rot, const float* __restrict__ trans, float* __restrict__ ws)
{
  int n = blockIdx.x; int t = threadIdx.x;
  __shared__ float sq[96];
  const float* R = rot + n*9; const float* T = trans + n*3;
  float R00=R[0],R01=R[1],R02=R[2],R10=R[3],R11=R[4],R12=R[5],R20=R[6],R21=R[7],R22=R[8];
  float T0=T[0],T1=T[1],T2=T[2];
  if (t < 96) {
    int isK = (t >= 48); int m = isK ? t - 48 : t;
    int h = m >> 2, p = m & 3;
    const float* L = ws + (isK ? WS_KPL : WS_QPL) + n*144 + h*12;
    float px = L[p], py = L[4 + p], pz = L[8 + p];
    float gx = R00*px + R01*py + R02*pz + T0;
    float gy = R10*px + R11*py + R12*pz + T1;
    float gz = R20*px + R21*py + R22*pz + T2;
    float* O = ws + (isK ? WS_KPT : WS_QPT) + n*144 + h*12 + p*3;
    O[0] = gx; O[1] = gy; O[2] = gz;
    sq[t] = gx*gx + gy*gy + gz*gz;
  } else {
    int m = t - 96; int h = m >> 3, p = m & 7;
    const float* L = ws + WS_VPL + n*288 + h*24;
    float px = L[p], py = L[8 + p], pz = L[16 + p];
    float gx = R00*px + R01*py + R02*pz + T0;
    float gy = R10*px + R11*py + R12*pz + T1;
    float gz = R20*px + R21*py + R22*pz + T2;
    float* O = ws + WS_VCAT + n*480 + 192 + h*24 + p*3;
    O[0] = gx; O[1] = gy; O[2] = gz;
  }
  __syncthreads();
  if (t < 12) {
    ws[WS_SQQ + n*12 + t] = sq[t*4] + sq[t*4+1] + sq[t*4+2] + sq[t*4+3];
  } else if (t < 24) {
    int h = t - 12;
    ws[WS_SQK + n*12 + h] = sq[48+h*4] + sq[48+h*4+1] + sq[48+h*4+2] + sq[48+h*4+3];
  }
}

// ---------------- K2: per-query fused attention -------------------------------
__global__ __launch_bounds__(512) void k_attn(
    const float* __restrict__ z, const float* __restrict__ mask,
    const float* __restrict__ w_b, const float* __restrict__ b_b,
    const float* __restrict__ head_weights,
    const float* __restrict__ rot, const float* __restrict__ trans,
    float* __restrict__ ws)
{
  int q = blockIdx.x; int tid = threadIdx.x;
  int lane = tid & 63; int wv = tid >> 6;
  int colh = lane & 15, g = lane >> 4;
  __shared__ float s_logits[NH * LQ];
  __shared__ short s_abf[16 * LQ];
  __shared__ float s_qv[192], s_qp[144], s_sqq[12], s_pw[12], s_bb[12];
  __shared__ float s_opt[288];
  const float* k_ws = ws + WS_K;
  const float* k_pts = ws + WS_KPT;
  const float* sq_k = ws + WS_SQK;
  const float* vcat = ws + WS_VCAT;
  float* cat = ws + WS_CAT;

  // phase 0: per-q data into LDS
  if (tid < 192) s_qv[tid] = ws[WS_Q + q*192 + tid];
  else if (tid < 336) s_qp[tid-192] = ws[WS_QPT + q*144 + (tid-192)];
  else if (tid < 348) s_sqq[tid-336] = ws[WS_SQQ + q*12 + (tid-336)];
  else if (tid < 360) {
    int h = tid - 348; float x = head_weights[h];
    float sp = fmaxf(x, 0.f) + log1pf(__expf(-fabsf(x)));       // softplus
    s_pw[h] = 0.23570226039551584f * sp;                        // sqrt(2/(9*4))
  }
  else if (tid < 372) s_bb[tid-360] = b_b[tid-360];
  for (int i = tid; i < 4*LQ; i += 512) s_abf[12*LQ + i] = 0;   // zero pad heads 12..15
  __syncthreads();

  // phase A1: qk + point-attn + biases (VALU)
  float maskq = mask[q];
  for (int i = tid; i < NRES*NH; i += 512) {
    int kk = i / 12, h = i % 12;
    const float* kv = k_ws + kk*192 + h*16;
    const float* qv = s_qv + h*16;
    float qk = 0.f;
    #pragma unroll
    for (int c = 0; c < 16; c++) qk += kv[c]*qv[c];
    const float* kp = k_pts + kk*144 + h*12;
    const float* qp = s_qp + h*12;
    float cr = 0.f;
    #pragma unroll
    for (int j = 0; j < 12; j++) cr += kp[j]*qp[j];
    float d2 = s_sqq[h] + sq_k[kk*12 + h] - 2.f*cr;
    float v = qk - 0.5f*s_pw[h]*d2 + s_bb[h] + INF_*(maskq*mask[kk] - 1.f);
    s_logits[h*LQ + kk] = v;
  }
  __syncthreads();

  // phase A2: b_bias = z @ w_b via MFMA, accumulate into logits
  bf16x8 wbf[4];
  #pragma unroll
  for (int ks = 0; ks < 4; ks++) {
    #pragma unroll
    for (int j = 0; j < 8; j++) {
      int c = ks*32 + g*8 + j;
      wbf[ks][j] = (colh < 12) ? f2bf(w_b[c*12 + colh]) : (short)0;
    }
  }
  for (int mtile = wv; mtile < 48; mtile += 8) {
    int k0 = mtile * 16;
    f32x4 acc = {0.f, 0.f, 0.f, 0.f};
    #pragma unroll
    for (int ks = 0; ks < 4; ks++) {
      bf16x8 av = pack8(z + ((size_t)q*NRES + k0 + colh)*CZ + ks*32 + g*8);
      acc = mfma16(av, wbf[ks], acc);
    }
    if (colh < 12) {
      #pragma unroll
      for (int r = 0; r < 4; r++)
        s_logits[colh*LQ + k0 + g*4 + r] += acc[r];
    }
  }
  __syncthreads();

  // phase A3: softmax over keys, per (h) row; write p fp32 + bf16
  for (int h = wv; h < NH; h += 8) {
    float v[12]; float m = -1e30f;
    #pragma unroll
    for (int i = 0; i < 12; i++) {
      v[i] = s_logits[h*LQ + lane + i*64] * 0.57735026919f;     // sqrt(1/3)
      m = fmaxf(m, v[i]);
    }
    #pragma unroll
    for (int d = 1; d < 64; d <<= 1) m = fmaxf(m, __shfl_xor(m, d));
    float sum = 0.f;
    #pragma unroll
    for (int i = 0; i < 12; i++) { v[i] = __expf(v[i] - m); sum += v[i]; }
    #pragma unroll
    for (int d = 1; d < 64; d <<= 1) sum += __shfl_xor(sum, d);
    float inv = 1.f / sum;
    #pragma unroll
    for (int i = 0; i < 12; i++) {
      float p = v[i] * inv;
      s_logits[h*LQ + lane + i*64] = p;
      s_abf[h*LQ + lane + i*64] = f2bf(p);
    }
  }
  __syncthreads();

  // phase B: o_pair = a^T @ z via MFMA (wave = 16-col tile of c_z)
  {
    int c0 = wv * 16;
    f32x4 acc = {0.f, 0.f, 0.f, 0.f};
    for (int ks = 0; ks < 24; ks++) {
      bf16x8 av = *(const bf16x8*)&s_abf[colh*LQ + ks*32 + g*8];
      const float* bp = z + ((size_t)q*NRES + ks*32 + g*8)*CZ + c0 + colh;
      bf16x8 bv;
      #pragma unroll
      for (int j = 0; j < 8; j++) bv[j] = f2bf(bp[(size_t)j*CZ]);
      acc = mfma16(av, bv, acc);
    }
    #pragma unroll
    for (int r = 0; r < 4; r++) {
      int hh = g*4 + r;
      if (hh < 12) cat[(size_t)q*CAT + 576 + hh*128 + c0 + colh] = acc[r];
    }
  }

  // phase C: o (scalar values) + o_pt (point values) from fused vcat
  if (tid < 480) {
    int oi = tid;
    int h = (oi < 192) ? (oi >> 4) : ((oi - 192) / 24);
    float acc = 0.f;
    #pragma unroll 4
    for (int k = 0; k < NRES; k += 4) {
      float4 p4 = *(const float4*)&s_logits[h*LQ + k];
      const float* vp = vcat + (size_t)k*480 + oi;
      acc += p4.x*vp[0] + p4.y*vp[480] + p4.z*vp[960] + p4.w*vp[1440];
    }
    if (oi < 192) cat[(size_t)q*CAT + oi] = acc;
    else s_opt[oi - 192] = acc;
  }
  __syncthreads();

  // phase D: back to local frame, norms
  if (tid < 96) {
    int m = tid;
    float x = s_opt[m*3], y = s_opt[m*3+1], zz = s_opt[m*3+2];
    const float* R = rot + q*9; const float* T = trans + q*3;
    float dx = x - T[0], dy = y - T[1], dz = zz - T[2];
    float lx = R[0]*dx + R[3]*dy + R[6]*dz;
    float ly = R[1]*dx + R[4]*dy + R[7]*dz;
    float lz = R[2]*dx + R[5]*dy + R[8]*dz;
    float n2 = lx*lx + ly*ly + lz*lz;
    cat[(size_t)q*CAT + 192 + m] = lx;
    cat[(size_t)q*CAT + 288 + m] = ly;
    cat[(size_t)q*CAT + 384 + m] = lz;
    cat[(size_t)q*CAT + 480 + m] = sqrtf(fmaxf(n2, 1e-16f));
  }
}

// ---------------- K5: out = cat @ w_out + b_out via MFMA ----------------------
__global__ __launch_bounds__(256) void k_out(
    const float* __restrict__ ws, const float* __restrict__ w_out,
    const float* __restrict__ b_out, float* __restrict__ out)
{
  const float* cat = ws + WS_CAT;
  int mt = blockIdx.x;                         // 0..47
  int wv = threadIdx.x >> 6, lane = threadIdx.x & 63;
  int nt = blockIdx.y*4 + wv;                  // 0..23
  int col = lane & 15, g = lane >> 4;
  float bias = b_out[nt*16 + col];
  f32x4 acc = {bias, bias, bias, bias};
  for (int ks = 0; ks < 66; ks++) {
    bf16x8 av = pack8(cat + (size_t)(mt*16 + col)*CAT + ks*32 + g*8);
    const float* bp = w_out + (size_t)(ks*32 + g*8)*CS + nt*16 + col;
    bf16x8 bv;
    #pragma unroll
    for (int j = 0; j < 8; j++) bv[j] = f2bf(bp[(size_t)j*CS]);
    acc = mfma16(av, bv, acc);
  }
  #pragma unroll
  for (int r = 0; r < 4; r++)
    out[(size_t)(mt*16 + g*4 + r)*CS + nt*16 + col] = acc[r];
}

extern "C" void kernel_launch(void* const* d_in, const int* in_sizes, int n_in,
                              void* d_out, int out_size, void* d_ws, size_t ws_size,
                              hipStream_t stream) {
  const float* s     = (const float*)d_in[0];
  const float* z     = (const float*)d_in[1];
  const float* mask  = (const float*)d_in[2];
  const float* rot   = (const float*)d_in[3];
  const float* trans = (const float*)d_in[4];
  const float* w_q   = (const float*)d_in[5];
  const float* w_k   = (const float*)d_in[6];
  const float* w_v   = (const float*)d_in[7];
  const float* w_qp  = (const float*)d_in[8];
  const float* b_qp  = (const float*)d_in[9];
  const float* w_kp  = (const float*)d_in[10];
  const float* b_kp  = (const float*)d_in[11];
  const float* w_vp  = (const float*)d_in[12];
  const float* b_vp  = (const float*)d_in[13];
  const float* w_b   = (const float*)d_in[14];
  const float* b_b   = (const float*)d_in[15];
  const float* hw    = (const float*)d_in[16];
  const float* w_out = (const float*)d_in[17];
  const float* b_out = (const float*)d_in[18];
  float* out = (float*)d_out;
  float* ws  = (float*)d_ws;

  k_proj <<<dim3(48, 18), 256, 0, stream>>>(s, w_q, w_k, w_v, w_qp, b_qp, w_kp, b_kp, w_vp, b_vp, ws);
  k_rigid<<<768, 192, 0, stream>>>(rot, trans, ws);
  k_attn <<<768, 512, 0, stream>>>(z, mask, w_b, b_b, hw, rot, trans, ws);
  k_out  <<<dim3(48, 6), 256, 0, stream>>>(ws, w_out, b_out, out);
}

// Round 5
// 608.891 us; speedup vs baseline: 1.0683x; 1.0683x over previous
//
#include <hip/hip_runtime.h>
#include <hip/hip_bf16.h>
#include <math.h>

#define NRES 768
#define CS 384
#define CZ 128
#define NH 12
#define INF_ 100000.0f
#define CAT 2112
#define LQF 775  // fp32 logits row stride (odd -> conflict-free banks)

typedef __attribute__((ext_vector_type(8))) short bf16x8;
typedef __attribute__((ext_vector_type(4))) float f32x4;

// bf16 'a' overlay inside s_logits: 16 rows x 768, XOR-swizzled.
// element index; row stride 768 shorts (1536 B); swizzle k ^= (row&7)<<3
#define ABF(row,k) ((row)*768 + ((k) ^ (((row)&7)<<3)))

// Workspace layout (float offsets)
#define WS_Q      0         // 768*192  q scaled by 0.25
#define WS_K      147456    // 768*192
#define WS_QPL    294912    // 768*144  raw linear q-points
#define WS_KPL    405504    // 768*144
#define WS_VPL    516096    // 768*288
#define WS_QPT    737280    // 768*144  transformed q_pts [n][h][p][3]
#define WS_KPT    847872    // 768*144
#define WS_SQQ    958464    // 768*12
#define WS_SQK    967680    // 768*12
#define WS_VCAT   976896    // 768*480  [n][ v(192) | v_pts(288) ]
#define WS_CAT    1345536   // 768*2112

__device__ __forceinline__ short f2bf(float f) {
  union { float f; unsigned u; } x; x.f = f;
  unsigned r = x.u + 0x7FFFu + ((x.u >> 16) & 1u);
  return (short)(r >> 16);
}

__device__ __forceinline__ float bf2f(short s) {
  union { unsigned u; float f; } t;
  t.u = ((unsigned)(unsigned short)s) << 16;
  return t.f;
}

__device__ __forceinline__ f32x4 mfma16(bf16x8 a, bf16x8 b, f32x4 c) {
  return __builtin_amdgcn_mfma_f32_16x16x32_bf16(a, b, c, 0, 0, 0);
}

__device__ __forceinline__ bf16x8 pack8(const float* p) {
  float4 a0 = *(const float4*)p;
  float4 a1 = *(const float4*)(p + 4);
  bf16x8 v;
  v[0] = f2bf(a0.x); v[1] = f2bf(a0.y); v[2] = f2bf(a0.z); v[3] = f2bf(a0.w);
  v[4] = f2bf(a1.x); v[5] = f2bf(a1.y); v[6] = f2bf(a1.z); v[7] = f2bf(a1.w);
  return v;
}

// ---------------- K1: all s-projections as one bf16 MFMA GEMM -----------------
__global__ __launch_bounds__(256) void k_proj(
    const float* __restrict__ s,
    const float* __restrict__ w_q, const float* __restrict__ w_k, const float* __restrict__ w_v,
    const float* __restrict__ w_qp, const float* __restrict__ b_qp,
    const float* __restrict__ w_kp, const float* __restrict__ b_kp,
    const float* __restrict__ w_vp, const float* __restrict__ b_vp,
    float* __restrict__ ws)
{
  int mt = blockIdx.x;                    // 0..47 (row tile)
  int wv = threadIdx.x >> 6;
  int lane = threadIdx.x & 63;
  int nt = blockIdx.y * 4 + wv;           // 0..71 (16-col tile)
  const float* W; const float* B = nullptr; int OC, j0, seg;
  if (nt < 12)      { W = w_q;  OC = 192; j0 = nt*16;       seg = 0; }
  else if (nt < 24) { W = w_k;  OC = 192; j0 = nt*16 - 192; seg = 1; }
  else if (nt < 36) { W = w_v;  OC = 192; j0 = nt*16 - 384; seg = 2; }
  else if (nt < 45) { W = w_qp; OC = 144; j0 = nt*16 - 576; seg = 3; B = b_qp; }
  else if (nt < 54) { W = w_kp; OC = 144; j0 = nt*16 - 720; seg = 4; B = b_kp; }
  else              { W = w_vp; OC = 288; j0 = nt*16 - 864; seg = 5; B = b_vp; }
  int col = lane & 15, g = lane >> 4;
  f32x4 acc = {0.f, 0.f, 0.f, 0.f};
  for (int ks = 0; ks < 12; ks++) {
    bf16x8 av = pack8(s + (size_t)(mt*16 + col)*CS + ks*32 + g*8);
    const float* bp = W + (size_t)(ks*32 + g*8)*OC + j0 + col;
    bf16x8 bv;
    #pragma unroll
    for (int j = 0; j < 8; j++) bv[j] = f2bf(bp[(size_t)j*OC]);
    acc = mfma16(av, bv, acc);
  }
  float bias = B ? B[j0 + col] : 0.f;
  float* q_ws = ws + WS_Q;  float* k_ws = ws + WS_K;
  float* qpl  = ws + WS_QPL; float* kpl = ws + WS_KPL; float* vpl = ws + WS_VPL;
  float* vcat = ws + WS_VCAT;
  int jc = j0 + col;
  #pragma unroll
  for (int r = 0; r < 4; r++) {
    int n = mt*16 + g*4 + r;
    float v = acc[r] + bias;
    switch (seg) {
      case 0: q_ws[n*192 + jc] = v * 0.25f; break;   // scalar_w = 1/sqrt(16)
      case 1: k_ws[n*192 + jc] = v; break;
      case 2: vcat[n*480 + jc] = v; break;
      case 3: qpl[n*144 + jc] = v; break;
      case 4: kpl[n*144 + jc] = v; break;
      default: vpl[n*288 + jc] = v; break;
    }
  }
}

// ---------------- K1b: rigid apply + squared norms ----------------------------
__global__ __launch_bounds__(192) void k_rigid(
    const float* __restrict__ rot, const float* __restrict__ trans, float* __restrict__ ws)
{
  int n = blockIdx.x; int t = threadIdx.x;
  __shared__ float sq[96];
  const float* R = rot + n*9; const float* T = trans + n*3;
  float R00=R[0],R01=R[1],R02=R[2],R10=R[3],R11=R[4],R12=R[5],R20=R[6],R21=R[7],R22=R[8];
  float T0=T[0],T1=T[1],T2=T[2];
  if (t < 96) {
    int isK = (t >= 48); int m = isK ? t - 48 : t;
    int h = m >> 2, p = m & 3;
    const float* L = ws + (isK ? WS_KPL : WS_QPL) + n*144 + h*12;
    float px = L[p], py = L[4 + p], pz = L[8 + p];
    float gx = R00*px + R01*py + R02*pz + T0;
    float gy = R10*px + R11*py + R12*pz + T1;
    float gz = R20*px + R21*py + R22*pz + T2;
    float* O = ws + (isK ? WS_KPT : WS_QPT) + n*144 + h*12 + p*3;
    O[0] = gx; O[1] = gy; O[2] = gz;
    sq[t] = gx*gx + gy*gy + gz*gz;
  } else {
    int m = t - 96; int h = m >> 3, p = m & 7;
    const float* L = ws + WS_VPL + n*288 + h*24;
    float px = L[p], py = L[8 + p], pz = L[16 + p];
    float gx = R00*px + R01*py + R02*pz + T0;
    float gy = R10*px + R11*py + R12*pz + T1;
    float gz = R20*px + R21*py + R22*pz + T2;
    float* O = ws + WS_VCAT + n*480 + 192 + h*24 + p*3;
    O[0] = gx; O[1] = gy; O[2] = gz;
  }
  __syncthreads();
  if (t < 12) {
    ws[WS_SQQ + n*12 + t] = sq[t*4] + sq[t*4+1] + sq[t*4+2] + sq[t*4+3];
  } else if (t < 24) {
    int h = t - 12;
    ws[WS_SQK + n*12 + h] = sq[48+h*4] + sq[48+h*4+1] + sq[48+h*4+2] + sq[48+h*4+3];
  }
}

// ---------------- K2: per-query fused attention -------------------------------
// LDS ~40 KB -> 3 blocks/CU -> all 768 blocks resident simultaneously.
__global__ __launch_bounds__(512, 6) void k_attn(
    const float* __restrict__ z, const float* __restrict__ mask,
    const float* __restrict__ w_b, const float* __restrict__ b_b,
    const float* __restrict__ head_weights,
    const float* __restrict__ rot, const float* __restrict__ trans,
    float* __restrict__ ws)
{
  int q = blockIdx.x; int tid = threadIdx.x;
  int lane = tid & 63; int wv = tid >> 6;
  int colh = lane & 15, g = lane >> 4;
  __shared__ float s_logits[NH * LQF];          // fp32 logits; bf16 'a' overlay after softmax
  short* s_abf = (short*)s_logits;              // 16 rows x 768 shorts (24.6 KB of the 37.2)
  __shared__ float s_qv[192], s_qp[144], s_sqq[12], s_pw[12], s_bb[12];
  __shared__ float s_opt[288];
  const float* k_ws = ws + WS_K;
  const float* k_pts = ws + WS_KPT;
  const float* sq_k = ws + WS_SQK;
  const float* vcat = ws + WS_VCAT;
  float* cat = ws + WS_CAT;

  // phase 0: per-q data into LDS
  if (tid < 192) s_qv[tid] = ws[WS_Q + q*192 + tid];
  else if (tid < 336) s_qp[tid-192] = ws[WS_QPT + q*144 + (tid-192)];
  else if (tid < 348) s_sqq[tid-336] = ws[WS_SQQ + q*12 + (tid-336)];
  else if (tid < 360) {
    int h = tid - 348; float x = head_weights[h];
    float sp = fmaxf(x, 0.f) + log1pf(__expf(-fabsf(x)));       // softplus
    s_pw[h] = 0.23570226039551584f * sp;                        // sqrt(2/(9*4))
  }
  else if (tid < 372) s_bb[tid-360] = b_b[tid-360];
  __syncthreads();

  // phase A1: qk + point-attn + biases (VALU)
  float maskq = mask[q];
  for (int i = tid; i < NRES*NH; i += 512) {
    int kk = i / 12, h = i % 12;
    const float* kv = k_ws + kk*192 + h*16;
    const float* qv = s_qv + h*16;
    float qk = 0.f;
    #pragma unroll
    for (int c = 0; c < 16; c++) qk += kv[c]*qv[c];
    const float* kp = k_pts + kk*144 + h*12;
    const float* qp = s_qp + h*12;
    float cr = 0.f;
    #pragma unroll
    for (int j = 0; j < 12; j++) cr += kp[j]*qp[j];
    float d2 = s_sqq[h] + sq_k[kk*12 + h] - 2.f*cr;
    float v = qk - 0.5f*s_pw[h]*d2 + s_bb[h] + INF_*(maskq*mask[kk] - 1.f);
    s_logits[h*LQF + kk] = v;
  }
  __syncthreads();

  // phase A2: b_bias = z @ w_b via MFMA, accumulate into logits (z pass #1)
  bf16x8 wbf[4];
  #pragma unroll
  for (int ks = 0; ks < 4; ks++) {
    #pragma unroll
    for (int j = 0; j < 8; j++) {
      int c = ks*32 + g*8 + j;
      wbf[ks][j] = (colh < 12) ? f2bf(w_b[c*12 + colh]) : (short)0;
    }
  }
  for (int mtile = wv; mtile < 48; mtile += 8) {
    int k0 = mtile * 16;
    f32x4 acc = {0.f, 0.f, 0.f, 0.f};
    #pragma unroll
    for (int ks = 0; ks < 4; ks++) {
      bf16x8 av = pack8(z + ((size_t)q*NRES + k0 + colh)*CZ + ks*32 + g*8);
      acc = mfma16(av, wbf[ks], acc);
    }
    if (colh < 12) {
      #pragma unroll
      for (int r = 0; r < 4; r++)
        s_logits[colh*LQF + k0 + g*4 + r] += acc[r];
    }
  }
  __syncthreads();

  // phase A3: softmax over keys. Two ordered passes so the bf16 overlay
  // (bytes of fp32 rows 0..7.9) never races fp32 reads (rows 8-11).
  {
    // pass 1: wave wv handles head wv (rows 0-7)
    float v[12]; float m = -1e30f;
    #pragma unroll
    for (int i = 0; i < 12; i++) {
      v[i] = s_logits[wv*LQF + lane + i*64] * 0.57735026919f;   // sqrt(1/3)
      m = fmaxf(m, v[i]);
    }
    #pragma unroll
    for (int d = 1; d < 64; d <<= 1) m = fmaxf(m, __shfl_xor(m, d));
    float sum = 0.f;
    #pragma unroll
    for (int i = 0; i < 12; i++) { v[i] = __expf(v[i] - m); sum += v[i]; }
    #pragma unroll
    for (int d = 1; d < 64; d <<= 1) sum += __shfl_xor(sum, d);
    float inv = 1.f / sum;
    __syncthreads();   // all fp32 reads of rows 0-7 complete chip... block-wide
    #pragma unroll
    for (int i = 0; i < 12; i++)
      s_abf[ABF(wv, lane + i*64)] = f2bf(v[i] * inv);
    if (wv < 4) {
      // pass 2: rows 8-11 (fp32 bytes disjoint from all bf16 writes)
      int h = wv + 8;
      float w[12]; float m2 = -1e30f;
      #pragma unroll
      for (int i = 0; i < 12; i++) {
        w[i] = s_logits[h*LQF + lane + i*64] * 0.57735026919f;
        m2 = fmaxf(m2, w[i]);
      }
      #pragma unroll
      for (int d = 1; d < 64; d <<= 1) m2 = fmaxf(m2, __shfl_xor(m2, d));
      float sum2 = 0.f;
      #pragma unroll
      for (int i = 0; i < 12; i++) { w[i] = __expf(w[i] - m2); sum2 += w[i]; }
      #pragma unroll
      for (int d = 1; d < 64; d <<= 1) sum2 += __shfl_xor(sum2, d);
      float inv2 = 1.f / sum2;
      #pragma unroll
      for (int i = 0; i < 12; i++)
        s_abf[ABF(h, lane + i*64)] = f2bf(w[i] * inv2);
    } else {
      // zero pad rows 12-15 (A-fragment rows for colh>=12)
      int h = wv + 8;
      #pragma unroll
      for (int i = 0; i < 12; i++)
        s_abf[ABF(h, lane + i*64)] = 0;
    }
  }
  __syncthreads();

  // phase B: o_pair = a^T @ z via MFMA (z pass #2; wave = 16-col tile of c_z)
  {
    int c0 = wv * 16;
    f32x4 acc = {0.f, 0.f, 0.f, 0.f};
    for (int ks = 0; ks < 24; ks++) {
      bf16x8 av = *(const bf16x8*)&s_abf[ABF(colh, ks*32 + g*8)];
      const float* bp = z + ((size_t)q*NRES + ks*32 + g*8)*CZ + c0 + colh;
      bf16x8 bv;
      #pragma unroll
      for (int j = 0; j < 8; j++) bv[j] = f2bf(bp[(size_t)j*CZ]);
      acc = mfma16(av, bv, acc);
    }
    #pragma unroll
    for (int r = 0; r < 4; r++) {
      int hh = g*4 + r;
      if (hh < 12) cat[(size_t)q*CAT + 576 + hh*128 + c0 + colh] = acc[r];
    }
  }

  // phase C: o (scalar values) + o_pt (point values) from fused vcat, bf16 p
  if (tid < 480) {
    int oi = tid;
    int h = (oi < 192) ? (oi >> 4) : ((oi - 192) / 24);
    float acc = 0.f;
    for (int k0 = 0; k0 < NRES; k0 += 8) {
      bf16x8 pv = *(const bf16x8*)&s_abf[ABF(h, k0)];
      const float* vp = vcat + (size_t)k0*480 + oi;
      #pragma unroll
      for (int j = 0; j < 8; j++)
        acc += bf2f(pv[j]) * vp[(size_t)j*480];
    }
    if (oi < 192) cat[(size_t)q*CAT + oi] = acc;
    else s_opt[oi - 192] = acc;
  }
  __syncthreads();

  // phase D: back to local frame, norms
  if (tid < 96) {
    int m = tid;
    float x = s_opt[m*3], y = s_opt[m*3+1], zz = s_opt[m*3+2];
    const float* R = rot + q*9; const float* T = trans + q*3;
    float dx = x - T[0], dy = y - T[1], dz = zz - T[2];
    float lx = R[0]*dx + R[3]*dy + R[6]*dz;
    float ly = R[1]*dx + R[4]*dy + R[7]*dz;
    float lz = R[2]*dx + R[5]*dy + R[8]*dz;
    float n2 = lx*lx + ly*ly + lz*lz;
    cat[(size_t)q*CAT + 192 + m] = lx;
    cat[(size_t)q*CAT + 288 + m] = ly;
    cat[(size_t)q*CAT + 384 + m] = lz;
    cat[(size_t)q*CAT + 480 + m] = sqrtf(fmaxf(n2, 1e-16f));
  }
}

// ---------------- K5: out = cat @ w_out + b_out via MFMA ----------------------
__global__ __launch_bounds__(256) void k_out(
    const float* __restrict__ ws, const float* __restrict__ w_out,
    const float* __restrict__ b_out, float* __restrict__ out)
{
  const float* cat = ws + WS_CAT;
  int mt = blockIdx.x;                         // 0..47
  int wv = threadIdx.x >> 6, lane = threadIdx.x & 63;
  int nt = blockIdx.y*4 + wv;                  // 0..23
  int col = lane & 15, g = lane >> 4;
  float bias = b_out[nt*16 + col];
  f32x4 acc = {bias, bias, bias, bias};
  for (int ks = 0; ks < 66; ks++) {
    bf16x8 av = pack8(cat + (size_t)(mt*16 + col)*CAT + ks*32 + g*8);
    const float* bp = w_out + (size_t)(ks*32 + g*8)*CS + nt*16 + col;
    bf16x8 bv;
    #pragma unroll
    for (int j = 0; j < 8; j++) bv[j] = f2bf(bp[(size_t)j*CS]);
    acc = mfma16(av, bv, acc);
  }
  #pragma unroll
  for (int r = 0; r < 4; r++)
    out[(size_t)(mt*16 + g*4 + r)*CS + nt*16 + col] = acc[r];
}

extern "C" void kernel_launch(void* const* d_in, const int* in_sizes, int n_in,
                              void* d_out, int out_size, void* d_ws, size_t ws_size,
                              hipStream_t stream) {
  const float* s     = (const float*)d_in[0];
  const float* z     = (const float*)d_in[1];
  const float* mask  = (const float*)d_in[2];
  const float* rot   = (const float*)d_in[3];
  const float* trans = (const float*)d_in[4];
  const float* w_q   = (const float*)d_in[5];
  const float* w_k   = (const float*)d_in[6];
  const float* w_v   = (const float*)d_in[7];
  const float* w_qp  = (const float*)d_in[8];
  const float* b_qp  = (const float*)d_in[9];
  const float* w_kp  = (const float*)d_in[10];
  const float* b_kp  = (const float*)d_in[11];
  const float* w_vp  = (const float*)d_in[12];
  const float* b_vp  = (const float*)d_in[13];
  const float* w_b   = (const float*)d_in[14];
  const float* b_b   = (const float*)d_in[15];
  const float* hw    = (const float*)d_in[16];
  const float* w_out = (const float*)d_in[17];
  const float* b_out = (const float*)d_in[18];
  float* out = (float*)d_out;
  float* ws  = (float*)d_ws;

  k_proj <<<dim3(48, 18), 256, 0, stream>>>(s, w_q, w_k, w_v, w_qp, b_qp, w_kp, b_kp, w_vp, b_vp, ws);
  k_rigid<<<768, 192, 0, stream>>>(rot, trans, ws);
  k_attn <<<768, 512, 0, stream>>>(z, mask, w_b, b_b, hw, rot, trans, ws);
  k_out  <<<dim3(48, 6), 256, 0, stream>>>(ws, w_out, b_out, out);
}